// Round 9
// baseline (328.636 us; speedup 1.0000x reference)
//
#include <hip/hip_runtime.h>
#include <hip/hip_bf16.h>

#define N_NODES 100000
#define N_EDGES 3200000
#define F_IN 256
#define D_OUT 64
#define BATCH 4096
#define N_FIELDS 20
#define N_ENTRIES (BATCH * N_FIELDS)          // 81920

#define NBUCKET 512
#define NPB 196                                // nodes per bucket
#define N_PAD (NBUCKET * NPB)                  // 100352
#define EPB 16384                              // edges per histogram/scatter block
#define NBLK ((N_EDGES + EPB - 1) / EPB)       // 196
#define BUCKET_CAP 8192
#define SCAN_B 512
#define NSB (N_PAD / SCAN_B)                   // 196
#define CNT_BLKS (N_ENTRIES / 256)             // 320
#define GEMM_BLKS ((N_NODES + 63) / 64)        // 1563

typedef short bf16x8 __attribute__((ext_vector_type(8)));
typedef float f32x4 __attribute__((ext_vector_type(4)));

static __device__ __forceinline__ unsigned short f2bf_bits(float x) {
    __hip_bfloat16 h = __float2bfloat16(x);
    return *reinterpret_cast<unsigned short*>(&h);
}

// ---- K0: W (f32, K x N) -> bf16 W^T (N x K) ----
__global__ void k_wtconv(const float* __restrict__ W, unsigned short* __restrict__ WTbf) {
    int i = blockIdx.x * blockDim.x + threadIdx.x;
    if (i >= D_OUT * F_IN) return;
    int n = i >> 8, k = i & 255;
    WTbf[i] = f2bf_bits(W[k * D_OUT + n]);
}

// ---- K1: standalone MFMA GEMM yf = X @ W (f32, unscaled). Direct per-lane
//      feat loads (empirically equal to LDS-staged; wt-only LDS 33.8KB ->
//      4 blocks/CU). Unfused from k_front for per-kernel attribution. ----
__global__ __launch_bounds__(256) void k_gemm_mfma(const float* __restrict__ feat,
                                                   const unsigned short* __restrict__ WTbf,
                                                   float* __restrict__ yf) {
    __shared__ unsigned short wt[64 * 264];
    int tid = threadIdx.x;
    {
        int r = tid >> 2, seg = tid & 3;
        const uint4* gsrc = (const uint4*)(WTbf + r * 256 + seg * 64);
        uint4* ldst = (uint4*)&wt[r * 264 + seg * 64];
#pragma unroll
        for (int q = 0; q < 8; q++) ldst[q] = gsrc[q];
    }
    __syncthreads();

    int wave = tid >> 6, lane = tid & 63;
    int quad = lane >> 4, m = lane & 15;
    int rowT = blockIdx.x * 64 + wave * 16;
    int row = rowT + m;
    int rowC = (row < N_NODES) ? row : (N_NODES - 1);
    const float* fb = feat + (size_t)rowC * F_IN + quad * 8;

    f32x4 acc0 = {0.f, 0.f, 0.f, 0.f};
    f32x4 acc1 = acc0, acc2 = acc0, acc3 = acc0;

#pragma unroll
    for (int kk = 0; kk < 8; kk++) {
        float4 x0 = *(const float4*)(fb + kk * 32);
        float4 x1 = *(const float4*)(fb + kk * 32 + 4);
        bf16x8 a;
        a[0] = (short)f2bf_bits(x0.x); a[1] = (short)f2bf_bits(x0.y);
        a[2] = (short)f2bf_bits(x0.z); a[3] = (short)f2bf_bits(x0.w);
        a[4] = (short)f2bf_bits(x1.x); a[5] = (short)f2bf_bits(x1.y);
        a[6] = (short)f2bf_bits(x1.z); a[7] = (short)f2bf_bits(x1.w);
        int kbase = kk * 32 + quad * 8;
        bf16x8 b0 = *(const bf16x8*)&wt[(0 * 16 + m) * 264 + kbase];
        bf16x8 b1 = *(const bf16x8*)&wt[(1 * 16 + m) * 264 + kbase];
        bf16x8 b2 = *(const bf16x8*)&wt[(2 * 16 + m) * 264 + kbase];
        bf16x8 b3 = *(const bf16x8*)&wt[(3 * 16 + m) * 264 + kbase];
        acc0 = __builtin_amdgcn_mfma_f32_16x16x32_bf16(a, b0, acc0, 0, 0, 0);
        acc1 = __builtin_amdgcn_mfma_f32_16x16x32_bf16(a, b1, acc1, 0, 0, 0);
        acc2 = __builtin_amdgcn_mfma_f32_16x16x32_bf16(a, b2, acc2, 0, 0, 0);
        acc3 = __builtin_amdgcn_mfma_f32_16x16x32_bf16(a, b3, acc3, 0, 0, 0);
    }

#pragma unroll
    for (int r = 0; r < 4; r++) {
        int rr = rowT + quad * 4 + r;
        if (rr < N_NODES) {
            size_t o = (size_t)rr * D_OUT + m;
            yf[o]      = acc0[r];
            yf[o + 16] = acc1[r];
            yf[o + 32] = acc2[r];
            yf[o + 48] = acc3[r];
        }
    }
}

// ---- K2: fused front — bucket histogram (all edges) | x entry-count+refBits ----
__global__ __launch_bounds__(256) void k_front(const uint4* __restrict__ dst4,
                                               unsigned short* __restrict__ perBlockCnt,
                                               const int* __restrict__ x,
                                               int* __restrict__ nodeEntCnt,
                                               unsigned* __restrict__ refBits) {
    __shared__ unsigned hist[NBUCKET];
    int tid = threadIdx.x;
    if (blockIdx.x < NBLK) {
        hist[tid] = 0;
        hist[tid + 256] = 0;
        __syncthreads();
        int base4 = blockIdx.x * (EPB / 4);
#pragma unroll
        for (int k = 0; k < EPB / 1024; k++) {
            int e4 = base4 + k * 256 + tid;
            if (e4 < N_EDGES / 4) {
                uint4 d = dst4[e4];
                atomicAdd(&hist[d.x / NPB], 1u);
                atomicAdd(&hist[d.y / NPB], 1u);
                atomicAdd(&hist[d.z / NPB], 1u);
                atomicAdd(&hist[d.w / NPB], 1u);
            }
        }
        __syncthreads();
        perBlockCnt[(tid) * NBLK + blockIdx.x] = (unsigned short)hist[tid];
        perBlockCnt[(tid + 256) * NBLK + blockIdx.x] = (unsigned short)hist[tid + 256];
    } else {
        int ent = (blockIdx.x - NBLK) * 256 + tid;
        if (ent < N_ENTRIES) {
            int node = x[ent];
            atomicAdd(&nodeEntCnt[node], 1);
            atomicOr(&refBits[node >> 5], 1u << (node & 31));
        }
    }
}

// ---- K3: fused scans — per-block x-count scan (512T) | per-bucket colscan ----
__global__ __launch_bounds__(512) void k_scans(const int* __restrict__ nodeEntCnt,
                                               int* __restrict__ localE,
                                               int* __restrict__ blockSumsE,
                                               unsigned short* __restrict__ perBlockCnt,
                                               int* __restrict__ bucketTot) {
    if (blockIdx.x < NSB) {
        __shared__ int sh[SCAN_B];
        int g = blockIdx.x * SCAN_B + threadIdx.x;
        int v = (g < N_PAD) ? nodeEntCnt[g] : 0;
        sh[threadIdx.x] = v;
        __syncthreads();
        for (int off = 1; off < SCAN_B; off <<= 1) {
            int t = (threadIdx.x >= off) ? sh[threadIdx.x - off] : 0;
            __syncthreads();
            sh[threadIdx.x] += t;
            __syncthreads();
        }
        int incl = sh[threadIdx.x];
        if (g < N_PAD) localE[g] = incl - v;
        if (threadIdx.x == SCAN_B - 1) blockSumsE[blockIdx.x] = incl;
    } else {
        int gw = ((blockIdx.x - NSB) * 512 + threadIdx.x) >> 6;
        int lane = threadIdx.x & 63;
        if (gw >= NBUCKET) return;
        unsigned running = 0;
        for (int c = 0; c < (NBLK + 63) / 64; c++) {
            int blk = c * 64 + lane;
            int idx = gw * NBLK + blk;
            unsigned v = (blk < NBLK) ? perBlockCnt[idx] : 0;
            unsigned orig = v;
#pragma unroll
            for (int d = 1; d < 64; d <<= 1) {
                unsigned t = __shfl_up(v, d, 64);
                if (lane >= d) v += t;
            }
            if (blk < NBLK) perBlockCnt[idx] = (unsigned short)(running + v - orig);
            running += __shfl(v, 63, 64);
        }
        if (lane == 0) bucketTot[gw] = (int)running;
    }
}

// ---- K4: fused base scans ----
__global__ __launch_bounds__(512) void k_base2(const int* __restrict__ bucketTot,
                                               int* __restrict__ bucketBase,
                                               const int* __restrict__ blockSumsE,
                                               int* __restrict__ blockBaseE) {
    __shared__ int sh[512];
    int tid = threadIdx.x;
    if (blockIdx.x == 0) {
        int v = bucketTot[tid];
        sh[tid] = v;
        __syncthreads();
        for (int off = 1; off < 512; off <<= 1) {
            int t = (tid >= off) ? sh[tid - off] : 0;
            __syncthreads();
            sh[tid] += t;
            __syncthreads();
        }
        bucketBase[tid] = sh[tid] - v;
        if (tid == NBUCKET - 1) bucketBase[NBUCKET] = sh[NBUCKET - 1];
    } else {
        int v = (tid < NSB) ? blockSumsE[tid] : 0;
        sh[tid] = v;
        __syncthreads();
        for (int off = 1; off < 512; off <<= 1) {
            int t = (tid >= off) ? sh[tid - off] : 0;
            __syncthreads();
            sh[tid] += t;
            __syncthreads();
        }
        if (tid < NSB) blockBaseE[tid] = sh[tid] - v;
    }
}

// ---- K5: fused scatters — edge bucket-scatter (direct writes) | x scatter ----
__global__ __launch_bounds__(256) void k_scatters(const uint4* __restrict__ src4,
                                                  const uint4* __restrict__ dst4,
                                                  const int* __restrict__ bucketBase,
                                                  const unsigned short* __restrict__ perBlockCnt,
                                                  unsigned* __restrict__ bucketData,
                                                  const int* __restrict__ x,
                                                  int* __restrict__ localE,
                                                  const int* __restrict__ blockBaseE,
                                                  int* __restrict__ entGrouped) {
    if (blockIdx.x < NBLK) {
        __shared__ unsigned slotBase[NBUCKET];
        slotBase[threadIdx.x] = (unsigned)bucketBase[threadIdx.x] +
                                (unsigned)perBlockCnt[threadIdx.x * NBLK + blockIdx.x];
        slotBase[threadIdx.x + 256] = (unsigned)bucketBase[threadIdx.x + 256] +
                                      (unsigned)perBlockCnt[(threadIdx.x + 256) * NBLK + blockIdx.x];
        __syncthreads();
        int base4 = blockIdx.x * (EPB / 4);
#pragma unroll
        for (int k = 0; k < EPB / 1024; k++) {
            int e4 = base4 + k * 256 + threadIdx.x;
            if (e4 < N_EDGES / 4) {
                uint4 s = src4[e4];
                uint4 d = dst4[e4];
                unsigned ss[4] = {s.x, s.y, s.z, s.w};
                unsigned dd[4] = {d.x, d.y, d.z, d.w};
#pragma unroll
                for (int j = 0; j < 4; j++) {
                    unsigned b = dd[j] / NPB;
                    unsigned ld = dd[j] - b * NPB;
                    unsigned slot = atomicAdd(&slotBase[b], 1u);
                    bucketData[slot] = ss[j] | (ld << 17);
                }
            }
        }
    } else {
        int ent = (blockIdx.x - NBLK) * 256 + threadIdx.x;
        if (ent < N_ENTRIES) {
            int node = x[ent];
            int posL = atomicAdd(&localE[node], 1);
            entGrouped[blockBaseE[node >> 9] + posL] = ent;
        }
    }
}

// ---- K6: per-bucket CSR build + y finalize ----
__global__ __launch_bounds__(256) void k_bucket_csr(unsigned* __restrict__ bucketData,
                                                    const int* __restrict__ bucketBase,
                                                    const unsigned* __restrict__ refBits,
                                                    int* __restrict__ rowStart,
                                                    unsigned short* __restrict__ deg,
                                                    const float* __restrict__ yf,
                                                    unsigned short* __restrict__ y) {
    __shared__ unsigned srcsorted[BUCKET_CAP];
    __shared__ unsigned nodeCount[NPB];
    __shared__ unsigned sscan[256];
    __shared__ unsigned cursor[NPB];
    __shared__ unsigned char refF[NPB];

    int b = blockIdx.x;
    int base = bucketBase[b];
    int cnt = bucketBase[b + 1] - base;
    if (cnt > BUCKET_CAP) cnt = BUCKET_CAP;
    int tid = threadIdx.x;

    for (int j = tid; j < NPB; j += 256) nodeCount[j] = 0;
    __syncthreads();

    for (int i = tid; i < cnt; i += 256) {
        unsigned w = bucketData[base + i];
        atomicAdd(&nodeCount[w >> 17], 1u);
    }
    __syncthreads();

    int firstNode = b * NPB;
    unsigned refCnt = 0;
    if (tid < NPB) {
        int node = firstNode + tid;
        unsigned isRef = (refBits[node >> 5] >> (node & 31)) & 1u;
        refF[tid] = (unsigned char)isRef;
        refCnt = isRef ? nodeCount[tid] : 0;
        deg[node] = (unsigned short)nodeCount[tid];
    }
    sscan[tid] = refCnt;
    __syncthreads();
    for (int off = 1; off < 256; off <<= 1) {
        unsigned t = (tid >= off) ? sscan[tid - off] : 0;
        __syncthreads();
        sscan[tid] += t;
        __syncthreads();
    }

    if (tid < NPB) {
        unsigned excl = sscan[tid] - refCnt;
        rowStart[firstNode + tid] = base + (int)excl;
        cursor[tid] = excl;
    }
    __syncthreads();

    for (int i = tid; i < cnt; i += 256) {
        unsigned w = bucketData[base + i];
        unsigned ld = w >> 17;
        if (refF[ld]) {
            unsigned slot = atomicAdd(&cursor[ld], 1u);
            srcsorted[slot] = w & 0x1FFFFu;
        }
    }
    __syncthreads();

    int refTotal = (int)sscan[255];
    for (int i = tid; i < refTotal; i += 256)
        bucketData[base + i] = srcsorted[i];

    // y finalize: 196 rows x 64 ch, float4 in / uint2 (4 bf16) out.
    for (int idx = tid; idx < NPB * 16; idx += 256) {
        int j = idx >> 4;
        int node = firstNode + j;
        if (node < N_NODES) {
            float ds = rsqrtf((float)nodeCount[j] + 1.0f);
            float4 v = ((const float4*)(yf + (size_t)node * D_OUT))[idx & 15];
            uint2 pw;
            pw.x = (unsigned)f2bf_bits(v.x * ds) | ((unsigned)f2bf_bits(v.y * ds) << 16);
            pw.y = (unsigned)f2bf_bits(v.z * ds) | ((unsigned)f2bf_bits(v.w * ds) << 16);
            ((uint2*)(y + (size_t)node * D_OUT))[idx & 15] = pw;
        }
    }
}

// ---- K7: dedup aggregation (unchanged) ----
static __device__ __forceinline__ void acc4(f32x4& a, uint2 v, float msk) {
    a[0] += msk * __uint_as_float(v.x << 16);
    a[1] += msk * __uint_as_float(v.x & 0xffff0000u);
    a[2] += msk * __uint_as_float(v.y << 16);
    a[3] += msk * __uint_as_float(v.y & 0xffff0000u);
}

__global__ __launch_bounds__(256) void k_agg(const int* __restrict__ entGrouped,
                                             const int* __restrict__ localE,
                                             const int* __restrict__ blockBaseE,
                                             const int* __restrict__ rowStart,
                                             const unsigned short* __restrict__ deg,
                                             const unsigned* __restrict__ sortedSrc,
                                             const unsigned short* __restrict__ y,
                                             const float* __restrict__ b,
                                             float* __restrict__ out) {
    int g = blockIdx.x * blockDim.x + threadIdx.x;
    int i = g >> 6, lane = g & 63;
    if (i >= N_PAD) return;
    int gEnd = blockBaseE[i >> 9] + localE[i];
    int gStart = (i == 0) ? 0 : (blockBaseE[(i - 1) >> 9] + localE[i - 1]);
    int cntEnt = gEnd - gStart;
    if (cntEnt <= 0) return;

    int grp = lane >> 4;
    int m = lane & 15;
    int start = rowStart[i];
    int cnt = deg[i];
    float disI = rsqrtf((float)(cnt + 1));

    uint2 sv = *(const uint2*)(y + ((unsigned)i << 6) + (m << 2));

    f32x4 a0 = {0.f, 0.f, 0.f, 0.f};
    f32x4 a1 = a0, a2 = a0, a3 = a0;

    for (int e = 0; e < cnt; e += 32) {
        int e0 = e + grp,      e1 = e + 4 + grp,  e2 = e + 8 + grp,  e3 = e + 12 + grp;
        int e4 = e + 16 + grp, e5 = e + 20 + grp, e6 = e + 24 + grp, e7 = e + 28 + grp;
        unsigned r0 = (e0 < cnt) ? sortedSrc[start + e0] : (unsigned)i;
        unsigned r1 = (e1 < cnt) ? sortedSrc[start + e1] : (unsigned)i;
        unsigned r2 = (e2 < cnt) ? sortedSrc[start + e2] : (unsigned)i;
        unsigned r3 = (e3 < cnt) ? sortedSrc[start + e3] : (unsigned)i;
        unsigned r4 = (e4 < cnt) ? sortedSrc[start + e4] : (unsigned)i;
        unsigned r5 = (e5 < cnt) ? sortedSrc[start + e5] : (unsigned)i;
        unsigned r6 = (e6 < cnt) ? sortedSrc[start + e6] : (unsigned)i;
        unsigned r7 = (e7 < cnt) ? sortedSrc[start + e7] : (unsigned)i;
        uint2 v0 = *(const uint2*)(y + (r0 << 6) + (m << 2));
        uint2 v1 = *(const uint2*)(y + (r1 << 6) + (m << 2));
        uint2 v2 = *(const uint2*)(y + (r2 << 6) + (m << 2));
        uint2 v3 = *(const uint2*)(y + (r3 << 6) + (m << 2));
        uint2 v4 = *(const uint2*)(y + (r4 << 6) + (m << 2));
        uint2 v5 = *(const uint2*)(y + (r5 << 6) + (m << 2));
        uint2 v6 = *(const uint2*)(y + (r6 << 6) + (m << 2));
        uint2 v7 = *(const uint2*)(y + (r7 << 6) + (m << 2));
        acc4(a0, v0, (e0 < cnt) ? 1.f : 0.f);
        acc4(a1, v1, (e1 < cnt) ? 1.f : 0.f);
        acc4(a2, v2, (e2 < cnt) ? 1.f : 0.f);
        acc4(a3, v3, (e3 < cnt) ? 1.f : 0.f);
        acc4(a0, v4, (e4 < cnt) ? 1.f : 0.f);
        acc4(a1, v5, (e5 < cnt) ? 1.f : 0.f);
        acc4(a2, v6, (e6 < cnt) ? 1.f : 0.f);
        acc4(a3, v7, (e7 < cnt) ? 1.f : 0.f);
    }

    f32x4 s;
#pragma unroll
    for (int c = 0; c < 4; c++) s[c] = (a0[c] + a1[c]) + (a2[c] + a3[c]);
#pragma unroll
    for (int c = 0; c < 4; c++) {
        s[c] += __shfl_xor(s[c], 16, 64);
        s[c] += __shfl_xor(s[c], 32, 64);
    }

    float4 b4 = *(const float4*)(b + (m << 2));
    float4 val;
    val.x = disI * (s[0] + __uint_as_float(sv.x << 16)) + b4.x;
    val.y = disI * (s[1] + __uint_as_float(sv.x & 0xffff0000u)) + b4.y;
    val.z = disI * (s[2] + __uint_as_float(sv.y << 16)) + b4.z;
    val.w = disI * (s[3] + __uint_as_float(sv.y & 0xffff0000u)) + b4.w;

    for (int j = grp; j < cntEnt; j += 4) {
        int ent = entGrouped[gStart + j];
        *(float4*)(out + (size_t)ent * D_OUT + (m << 2)) = val;
    }
}

extern "C" void kernel_launch(void* const* d_in, const int* in_sizes, int n_in,
                              void* d_out, int out_size, void* d_ws, size_t ws_size,
                              hipStream_t stream) {
    const float* feat     = (const float*)d_in[0];
    const int* edge_index = (const int*)d_in[1];
    const float* W        = (const float*)d_in[2];
    const float* bsrc     = (const float*)d_in[3];
    const int* x          = (const int*)d_in[4];
    float* out            = (float*)d_out;

    const uint4* src4 = (const uint4*)edge_index;
    const uint4* dst4 = (const uint4*)(edge_index + N_EDGES);

    // workspace layout (256B aligned) — ~52 MB total (ws >= 400 MB).
    // aliases: ecOff region = nodeEntCnt (dead after k_scans) -> entGrouped.
    //          rsOff region = perBlockCnt (dead after k_scatters) -> rowStart.
    char* ws = (char*)d_ws;
    size_t off = 0;
    auto alloc = [&](size_t bytes) {
        size_t o = off;
        off = (off + bytes + 255) & ~(size_t)255;
        return o;
    };
    int* bucketBase = (int*)(ws + alloc((size_t)(NBUCKET + 1) * 4));
    int* bucketTot  = (int*)(ws + alloc((size_t)NBUCKET * 4));
    size_t ecOff = alloc((size_t)N_PAD * 4);
    int* nodeEntCnt = (int*)(ws + ecOff);
    int* entGrouped = (int*)(ws + ecOff);
    unsigned* refBits = (unsigned*)(ws + alloc((size_t)(N_PAD / 8)));
    size_t rsOff = alloc((size_t)N_PAD * 4);   // 401,408 B >= 512*196*2
    unsigned short* perBlockCnt = (unsigned short*)(ws + rsOff);
    int* rowStart   = (int*)(ws + rsOff);
    unsigned short* deg = (unsigned short*)(ws + alloc((size_t)N_PAD * 2));
    unsigned short* WTbf = (unsigned short*)(ws + alloc((size_t)D_OUT * F_IN * 2));
    int* localE     = (int*)(ws + alloc((size_t)N_PAD * 4));
    int* blockSumsE = (int*)(ws + alloc((size_t)NSB * 4));
    int* blockBaseE = (int*)(ws + alloc((size_t)NSB * 4));
    unsigned* bucketData = (unsigned*)(ws + alloc((size_t)N_EDGES * 4));
    unsigned short* y = (unsigned short*)(ws + alloc((size_t)N_NODES * D_OUT * 2));
    float* yf       = (float*)(ws + alloc((size_t)N_NODES * D_OUT * 4));
    (void)ws_size; (void)in_sizes; (void)n_in; (void)out_size;

    const int T = 256;
    (void)hipMemsetAsync(nodeEntCnt, 0, (size_t)N_PAD * 4, stream);
    (void)hipMemsetAsync(refBits, 0, (size_t)(N_PAD / 8), stream);
    k_wtconv<<<(D_OUT * F_IN + T - 1) / T, T, 0, stream>>>(W, WTbf);
    k_gemm_mfma<<<GEMM_BLKS, T, 0, stream>>>(feat, WTbf, yf);
    k_front<<<NBLK + CNT_BLKS, T, 0, stream>>>(dst4, perBlockCnt, x, nodeEntCnt, refBits);
    k_scans<<<NSB + 64, 512, 0, stream>>>(nodeEntCnt, localE, blockSumsE, perBlockCnt, bucketTot);
    k_base2<<<2, 512, 0, stream>>>(bucketTot, bucketBase, blockSumsE, blockBaseE);
    k_scatters<<<NBLK + CNT_BLKS, T, 0, stream>>>(src4, dst4, bucketBase, perBlockCnt, bucketData,
                                                  x, localE, blockBaseE, entGrouped);
    k_bucket_csr<<<NBUCKET, T, 0, stream>>>(bucketData, bucketBase, refBits, rowStart, deg, yf, y);
    k_agg<<<((size_t)N_PAD * 64 + T - 1) / T, T, 0, stream>>>(
        entGrouped, localE, blockBaseE, rowStart, deg, bucketData, y, bsrc, out);
}

// Round 10
// 314.505 us; speedup vs baseline: 1.0449x; 1.0449x over previous
//
#include <hip/hip_runtime.h>
#include <hip/hip_bf16.h>

#define N_NODES 100000
#define N_EDGES 3200000
#define F_IN 256
#define D_OUT 64
#define BATCH 4096
#define N_FIELDS 20
#define N_ENTRIES (BATCH * N_FIELDS)          // 81920

#define NBUCKET 512
#define NPB 196                                // nodes per bucket
#define N_PAD (NBUCKET * NPB)                  // 100352
#define EPB 4096                               // edges per histogram/scatter block
#define NBLK ((N_EDGES + EPB - 1) / EPB)       // 782
#define BUCKET_CAP 8192
#define SCAN_B 512
#define NSB (N_PAD / SCAN_B)                   // 196
#define CNT_BLKS (N_ENTRIES / 256)             // 320
#define GEMM_BLKS ((N_NODES + 63) / 64)        // 1563

typedef short bf16x8 __attribute__((ext_vector_type(8)));
typedef float f32x4 __attribute__((ext_vector_type(4)));

static __device__ __forceinline__ unsigned short f2bf_bits(float x) {
    __hip_bfloat16 h = __float2bfloat16(x);
    return *reinterpret_cast<unsigned short*>(&h);
}

// ---- K1: fused front — bucket histogram (782 blks) | x entry-count+refBits
//      (320 blks) | MFMA GEMM yf = X @ W (1563 blks, f32 out, unscaled).
//      GEMM blocks build wt in LDS directly from W (L2-hot, same rounding).
//      LDS = hist 2KB + wt 33.8KB = 35.8KB -> 4 blocks/CU. ----
__global__ __launch_bounds__(256) void k_front(const uint4* __restrict__ dst4,
                                               unsigned short* __restrict__ perBlockCnt,
                                               const int* __restrict__ x,
                                               int* __restrict__ nodeEntCnt,
                                               unsigned* __restrict__ refBits,
                                               const float* __restrict__ feat,
                                               const float* __restrict__ W,
                                               float* __restrict__ yf) {
    __shared__ unsigned hist[NBUCKET];
    __shared__ unsigned short wt[64 * 264];
    int tid = threadIdx.x;

    if (blockIdx.x < NBLK) {
        hist[tid] = 0;
        hist[tid + 256] = 0;
        __syncthreads();
        int base4 = blockIdx.x * (EPB / 4);
#pragma unroll
        for (int k = 0; k < EPB / 1024; k++) {
            int e4 = base4 + k * 256 + tid;
            if (e4 < N_EDGES / 4) {
                uint4 d = dst4[e4];
                atomicAdd(&hist[d.x / NPB], 1u);
                atomicAdd(&hist[d.y / NPB], 1u);
                atomicAdd(&hist[d.z / NPB], 1u);
                atomicAdd(&hist[d.w / NPB], 1u);
            }
        }
        __syncthreads();
        perBlockCnt[(tid) * NBLK + blockIdx.x] = (unsigned short)hist[tid];
        perBlockCnt[(tid + 256) * NBLK + blockIdx.x] = (unsigned short)hist[tid + 256];
    } else if (blockIdx.x < NBLK + CNT_BLKS) {
        int ent = (blockIdx.x - NBLK) * 256 + tid;
        if (ent < N_ENTRIES) {
            int node = x[ent];
            atomicAdd(&nodeEntCnt[node], 1);
            atomicOr(&refBits[node >> 5], 1u << (node & 31));
        }
    } else {
        int gb = blockIdx.x - NBLK - CNT_BLKS;
        // build wt[n*264+k] = bf16(W[k*64+n]); thread tid owns k=tid
        {
            const float4* wrow = (const float4*)(W + tid * 64);
#pragma unroll
            for (int n4 = 0; n4 < 16; n4++) {
                float4 v = wrow[n4];
                wt[(n4 * 4 + 0) * 264 + tid] = f2bf_bits(v.x);
                wt[(n4 * 4 + 1) * 264 + tid] = f2bf_bits(v.y);
                wt[(n4 * 4 + 2) * 264 + tid] = f2bf_bits(v.z);
                wt[(n4 * 4 + 3) * 264 + tid] = f2bf_bits(v.w);
            }
        }
        __syncthreads();

        int wave = tid >> 6, lane = tid & 63;
        int quad = lane >> 4, m = lane & 15;
        int rowT = gb * 64 + wave * 16;
        int row = rowT + m;
        int rowC = (row < N_NODES) ? row : (N_NODES - 1);
        const float* fb = feat + (size_t)rowC * F_IN + quad * 8;

        f32x4 acc0 = {0.f, 0.f, 0.f, 0.f};
        f32x4 acc1 = acc0, acc2 = acc0, acc3 = acc0;

#pragma unroll
        for (int kk = 0; kk < 8; kk++) {
            float4 x0 = *(const float4*)(fb + kk * 32);
            float4 x1 = *(const float4*)(fb + kk * 32 + 4);
            bf16x8 a;
            a[0] = (short)f2bf_bits(x0.x); a[1] = (short)f2bf_bits(x0.y);
            a[2] = (short)f2bf_bits(x0.z); a[3] = (short)f2bf_bits(x0.w);
            a[4] = (short)f2bf_bits(x1.x); a[5] = (short)f2bf_bits(x1.y);
            a[6] = (short)f2bf_bits(x1.z); a[7] = (short)f2bf_bits(x1.w);
            int kbase = kk * 32 + quad * 8;
            bf16x8 b0 = *(const bf16x8*)&wt[(0 * 16 + m) * 264 + kbase];
            bf16x8 b1 = *(const bf16x8*)&wt[(1 * 16 + m) * 264 + kbase];
            bf16x8 b2 = *(const bf16x8*)&wt[(2 * 16 + m) * 264 + kbase];
            bf16x8 b3 = *(const bf16x8*)&wt[(3 * 16 + m) * 264 + kbase];
            acc0 = __builtin_amdgcn_mfma_f32_16x16x32_bf16(a, b0, acc0, 0, 0, 0);
            acc1 = __builtin_amdgcn_mfma_f32_16x16x32_bf16(a, b1, acc1, 0, 0, 0);
            acc2 = __builtin_amdgcn_mfma_f32_16x16x32_bf16(a, b2, acc2, 0, 0, 0);
            acc3 = __builtin_amdgcn_mfma_f32_16x16x32_bf16(a, b3, acc3, 0, 0, 0);
        }

#pragma unroll
        for (int r = 0; r < 4; r++) {
            int rr = rowT + quad * 4 + r;
            if (rr < N_NODES) {
                size_t o = (size_t)rr * D_OUT + m;
                yf[o]      = acc0[r];
                yf[o + 16] = acc1[r];
                yf[o + 32] = acc2[r];
                yf[o + 48] = acc3[r];
            }
        }
    }
}

// ---- K2: fused scans — per-block x-count scan (512T) | per-bucket colscan ----
__global__ __launch_bounds__(512) void k_scans(const int* __restrict__ nodeEntCnt,
                                               int* __restrict__ localE,
                                               int* __restrict__ blockSumsE,
                                               unsigned short* __restrict__ perBlockCnt,
                                               int* __restrict__ bucketTot) {
    if (blockIdx.x < NSB) {
        __shared__ int sh[SCAN_B];
        int g = blockIdx.x * SCAN_B + threadIdx.x;
        int v = (g < N_PAD) ? nodeEntCnt[g] : 0;
        sh[threadIdx.x] = v;
        __syncthreads();
        for (int off = 1; off < SCAN_B; off <<= 1) {
            int t = (threadIdx.x >= off) ? sh[threadIdx.x - off] : 0;
            __syncthreads();
            sh[threadIdx.x] += t;
            __syncthreads();
        }
        int incl = sh[threadIdx.x];
        if (g < N_PAD) localE[g] = incl - v;
        if (threadIdx.x == SCAN_B - 1) blockSumsE[blockIdx.x] = incl;
    } else {
        int gw = ((blockIdx.x - NSB) * 512 + threadIdx.x) >> 6;
        int lane = threadIdx.x & 63;
        if (gw >= NBUCKET) return;
        unsigned running = 0;
        for (int c = 0; c < (NBLK + 63) / 64; c++) {
            int blk = c * 64 + lane;
            int idx = gw * NBLK + blk;
            unsigned v = (blk < NBLK) ? perBlockCnt[idx] : 0;
            unsigned orig = v;
#pragma unroll
            for (int d = 1; d < 64; d <<= 1) {
                unsigned t = __shfl_up(v, d, 64);
                if (lane >= d) v += t;
            }
            if (blk < NBLK) perBlockCnt[idx] = (unsigned short)(running + v - orig);
            running += __shfl(v, 63, 64);
        }
        if (lane == 0) bucketTot[gw] = (int)running;
    }
}

// ---- K3: fused base scans ----
__global__ __launch_bounds__(512) void k_base2(const int* __restrict__ bucketTot,
                                               int* __restrict__ bucketBase,
                                               const int* __restrict__ blockSumsE,
                                               int* __restrict__ blockBaseE) {
    __shared__ int sh[512];
    int tid = threadIdx.x;
    if (blockIdx.x == 0) {
        int v = bucketTot[tid];
        sh[tid] = v;
        __syncthreads();
        for (int off = 1; off < 512; off <<= 1) {
            int t = (tid >= off) ? sh[tid - off] : 0;
            __syncthreads();
            sh[tid] += t;
            __syncthreads();
        }
        bucketBase[tid] = sh[tid] - v;
        if (tid == NBUCKET - 1) bucketBase[NBUCKET] = sh[NBUCKET - 1];
    } else {
        int v = (tid < NSB) ? blockSumsE[tid] : 0;
        sh[tid] = v;
        __syncthreads();
        for (int off = 1; off < 512; off <<= 1) {
            int t = (tid >= off) ? sh[tid - off] : 0;
            __syncthreads();
            sh[tid] += t;
            __syncthreads();
        }
        if (tid < NSB) blockBaseE[tid] = sh[tid] - v;
    }
}

// ---- K4: fused scatters — edge bucket-scatter (direct writes) | x scatter ----
__global__ __launch_bounds__(256) void k_scatters(const uint4* __restrict__ src4,
                                                  const uint4* __restrict__ dst4,
                                                  const int* __restrict__ bucketBase,
                                                  const unsigned short* __restrict__ perBlockCnt,
                                                  unsigned* __restrict__ bucketData,
                                                  const int* __restrict__ x,
                                                  int* __restrict__ localE,
                                                  const int* __restrict__ blockBaseE,
                                                  int* __restrict__ entGrouped) {
    if (blockIdx.x < NBLK) {
        __shared__ unsigned slotBase[NBUCKET];
        slotBase[threadIdx.x] = (unsigned)bucketBase[threadIdx.x] +
                                (unsigned)perBlockCnt[threadIdx.x * NBLK + blockIdx.x];
        slotBase[threadIdx.x + 256] = (unsigned)bucketBase[threadIdx.x + 256] +
                                      (unsigned)perBlockCnt[(threadIdx.x + 256) * NBLK + blockIdx.x];
        __syncthreads();
        int base4 = blockIdx.x * (EPB / 4);
#pragma unroll
        for (int k = 0; k < EPB / 1024; k++) {
            int e4 = base4 + k * 256 + threadIdx.x;
            if (e4 < N_EDGES / 4) {
                uint4 s = src4[e4];
                uint4 d = dst4[e4];
                unsigned ss[4] = {s.x, s.y, s.z, s.w};
                unsigned dd[4] = {d.x, d.y, d.z, d.w};
#pragma unroll
                for (int j = 0; j < 4; j++) {
                    unsigned b = dd[j] / NPB;
                    unsigned ld = dd[j] - b * NPB;
                    unsigned slot = atomicAdd(&slotBase[b], 1u);
                    bucketData[slot] = ss[j] | (ld << 17);
                }
            }
        }
    } else {
        int ent = (blockIdx.x - NBLK) * 256 + threadIdx.x;
        if (ent < N_ENTRIES) {
            int node = x[ent];
            int posL = atomicAdd(&localE[node], 1);
            entGrouped[blockBaseE[node >> 9] + posL] = ent;
        }
    }
}

// ---- K5: per-bucket CSR build + y finalize ----
__global__ __launch_bounds__(256) void k_bucket_csr(unsigned* __restrict__ bucketData,
                                                    const int* __restrict__ bucketBase,
                                                    const unsigned* __restrict__ refBits,
                                                    int* __restrict__ rowStart,
                                                    unsigned short* __restrict__ deg,
                                                    const float* __restrict__ yf,
                                                    unsigned short* __restrict__ y) {
    __shared__ unsigned srcsorted[BUCKET_CAP];
    __shared__ unsigned nodeCount[NPB];
    __shared__ unsigned sscan[256];
    __shared__ unsigned cursor[NPB];
    __shared__ unsigned char refF[NPB];

    int b = blockIdx.x;
    int base = bucketBase[b];
    int cnt = bucketBase[b + 1] - base;
    if (cnt > BUCKET_CAP) cnt = BUCKET_CAP;
    int tid = threadIdx.x;

    for (int j = tid; j < NPB; j += 256) nodeCount[j] = 0;
    __syncthreads();

    for (int i = tid; i < cnt; i += 256) {
        unsigned w = bucketData[base + i];
        atomicAdd(&nodeCount[w >> 17], 1u);
    }
    __syncthreads();

    int firstNode = b * NPB;
    unsigned refCnt = 0;
    if (tid < NPB) {
        int node = firstNode + tid;
        unsigned isRef = (refBits[node >> 5] >> (node & 31)) & 1u;
        refF[tid] = (unsigned char)isRef;
        refCnt = isRef ? nodeCount[tid] : 0;
        deg[node] = (unsigned short)nodeCount[tid];
    }
    sscan[tid] = refCnt;
    __syncthreads();
    for (int off = 1; off < 256; off <<= 1) {
        unsigned t = (tid >= off) ? sscan[tid - off] : 0;
        __syncthreads();
        sscan[tid] += t;
        __syncthreads();
    }

    if (tid < NPB) {
        unsigned excl = sscan[tid] - refCnt;
        rowStart[firstNode + tid] = base + (int)excl;
        cursor[tid] = excl;
    }
    __syncthreads();

    for (int i = tid; i < cnt; i += 256) {
        unsigned w = bucketData[base + i];
        unsigned ld = w >> 17;
        if (refF[ld]) {
            unsigned slot = atomicAdd(&cursor[ld], 1u);
            srcsorted[slot] = w & 0x1FFFFu;
        }
    }
    __syncthreads();

    int refTotal = (int)sscan[255];
    for (int i = tid; i < refTotal; i += 256)
        bucketData[base + i] = srcsorted[i];

    // y finalize: 196 rows x 64 ch, float4 in / uint2 (4 bf16) out.
    for (int idx = tid; idx < NPB * 16; idx += 256) {
        int j = idx >> 4;
        int node = firstNode + j;
        if (node < N_NODES) {
            float ds = rsqrtf((float)nodeCount[j] + 1.0f);
            float4 v = ((const float4*)(yf + (size_t)node * D_OUT))[idx & 15];
            uint2 pw;
            pw.x = (unsigned)f2bf_bits(v.x * ds) | ((unsigned)f2bf_bits(v.y * ds) << 16);
            pw.y = (unsigned)f2bf_bits(v.z * ds) | ((unsigned)f2bf_bits(v.w * ds) << 16);
            ((uint2*)(y + (size_t)node * D_OUT))[idx & 15] = pw;
        }
    }
}

// ---- K6: dedup aggregation (unchanged) ----
static __device__ __forceinline__ void acc4(f32x4& a, uint2 v, float msk) {
    a[0] += msk * __uint_as_float(v.x << 16);
    a[1] += msk * __uint_as_float(v.x & 0xffff0000u);
    a[2] += msk * __uint_as_float(v.y << 16);
    a[3] += msk * __uint_as_float(v.y & 0xffff0000u);
}

__global__ __launch_bounds__(256) void k_agg(const int* __restrict__ entGrouped,
                                             const int* __restrict__ localE,
                                             const int* __restrict__ blockBaseE,
                                             const int* __restrict__ rowStart,
                                             const unsigned short* __restrict__ deg,
                                             const unsigned* __restrict__ sortedSrc,
                                             const unsigned short* __restrict__ y,
                                             const float* __restrict__ b,
                                             float* __restrict__ out) {
    int g = blockIdx.x * blockDim.x + threadIdx.x;
    int i = g >> 6, lane = g & 63;
    if (i >= N_PAD) return;
    int gEnd = blockBaseE[i >> 9] + localE[i];
    int gStart = (i == 0) ? 0 : (blockBaseE[(i - 1) >> 9] + localE[i - 1]);
    int cntEnt = gEnd - gStart;
    if (cntEnt <= 0) return;

    int grp = lane >> 4;
    int m = lane & 15;
    int start = rowStart[i];
    int cnt = deg[i];
    float disI = rsqrtf((float)(cnt + 1));

    uint2 sv = *(const uint2*)(y + ((unsigned)i << 6) + (m << 2));

    f32x4 a0 = {0.f, 0.f, 0.f, 0.f};
    f32x4 a1 = a0, a2 = a0, a3 = a0;

    for (int e = 0; e < cnt; e += 32) {
        int e0 = e + grp,      e1 = e + 4 + grp,  e2 = e + 8 + grp,  e3 = e + 12 + grp;
        int e4 = e + 16 + grp, e5 = e + 20 + grp, e6 = e + 24 + grp, e7 = e + 28 + grp;
        unsigned r0 = (e0 < cnt) ? sortedSrc[start + e0] : (unsigned)i;
        unsigned r1 = (e1 < cnt) ? sortedSrc[start + e1] : (unsigned)i;
        unsigned r2 = (e2 < cnt) ? sortedSrc[start + e2] : (unsigned)i;
        unsigned r3 = (e3 < cnt) ? sortedSrc[start + e3] : (unsigned)i;
        unsigned r4 = (e4 < cnt) ? sortedSrc[start + e4] : (unsigned)i;
        unsigned r5 = (e5 < cnt) ? sortedSrc[start + e5] : (unsigned)i;
        unsigned r6 = (e6 < cnt) ? sortedSrc[start + e6] : (unsigned)i;
        unsigned r7 = (e7 < cnt) ? sortedSrc[start + e7] : (unsigned)i;
        uint2 v0 = *(const uint2*)(y + (r0 << 6) + (m << 2));
        uint2 v1 = *(const uint2*)(y + (r1 << 6) + (m << 2));
        uint2 v2 = *(const uint2*)(y + (r2 << 6) + (m << 2));
        uint2 v3 = *(const uint2*)(y + (r3 << 6) + (m << 2));
        uint2 v4 = *(const uint2*)(y + (r4 << 6) + (m << 2));
        uint2 v5 = *(const uint2*)(y + (r5 << 6) + (m << 2));
        uint2 v6 = *(const uint2*)(y + (r6 << 6) + (m << 2));
        uint2 v7 = *(const uint2*)(y + (r7 << 6) + (m << 2));
        acc4(a0, v0, (e0 < cnt) ? 1.f : 0.f);
        acc4(a1, v1, (e1 < cnt) ? 1.f : 0.f);
        acc4(a2, v2, (e2 < cnt) ? 1.f : 0.f);
        acc4(a3, v3, (e3 < cnt) ? 1.f : 0.f);
        acc4(a0, v4, (e4 < cnt) ? 1.f : 0.f);
        acc4(a1, v5, (e5 < cnt) ? 1.f : 0.f);
        acc4(a2, v6, (e6 < cnt) ? 1.f : 0.f);
        acc4(a3, v7, (e7 < cnt) ? 1.f : 0.f);
    }

    f32x4 s;
#pragma unroll
    for (int c = 0; c < 4; c++) s[c] = (a0[c] + a1[c]) + (a2[c] + a3[c]);
#pragma unroll
    for (int c = 0; c < 4; c++) {
        s[c] += __shfl_xor(s[c], 16, 64);
        s[c] += __shfl_xor(s[c], 32, 64);
    }

    float4 b4 = *(const float4*)(b + (m << 2));
    float4 val;
    val.x = disI * (s[0] + __uint_as_float(sv.x << 16)) + b4.x;
    val.y = disI * (s[1] + __uint_as_float(sv.x & 0xffff0000u)) + b4.y;
    val.z = disI * (s[2] + __uint_as_float(sv.y << 16)) + b4.z;
    val.w = disI * (s[3] + __uint_as_float(sv.y & 0xffff0000u)) + b4.w;

    for (int j = grp; j < cntEnt; j += 4) {
        int ent = entGrouped[gStart + j];
        *(float4*)(out + (size_t)ent * D_OUT + (m << 2)) = val;
    }
}

extern "C" void kernel_launch(void* const* d_in, const int* in_sizes, int n_in,
                              void* d_out, int out_size, void* d_ws, size_t ws_size,
                              hipStream_t stream) {
    const float* feat     = (const float*)d_in[0];
    const int* edge_index = (const int*)d_in[1];
    const float* W        = (const float*)d_in[2];
    const float* bsrc     = (const float*)d_in[3];
    const int* x          = (const int*)d_in[4];
    float* out            = (float*)d_out;

    const uint4* src4 = (const uint4*)edge_index;
    const uint4* dst4 = (const uint4*)(edge_index + N_EDGES);

    // workspace layout (256B aligned) — ~53 MB total (ws >= 400 MB).
    // aliases: ecOff region = nodeEntCnt (dead after k_scans) -> entGrouped.
    //          rsOff region = perBlockCnt (dead after k_scatters) -> rowStart.
    //          rsOff region sized for max(NBUCKET*NBLK*2, N_PAD*4).
    char* ws = (char*)d_ws;
    size_t off = 0;
    auto alloc = [&](size_t bytes) {
        size_t o = off;
        off = (off + bytes + 255) & ~(size_t)255;
        return o;
    };
    size_t pcBytes = (size_t)NBUCKET * NBLK * 2;             // 800,768
    size_t rsBytes = (pcBytes > (size_t)N_PAD * 4) ? pcBytes : (size_t)N_PAD * 4;
    int* bucketBase = (int*)(ws + alloc((size_t)(NBUCKET + 1) * 4));
    int* bucketTot  = (int*)(ws + alloc((size_t)NBUCKET * 4));
    size_t ecOff = alloc((size_t)N_PAD * 4);
    int* nodeEntCnt = (int*)(ws + ecOff);
    int* entGrouped = (int*)(ws + ecOff);
    unsigned* refBits = (unsigned*)(ws + alloc((size_t)(N_PAD / 8)));
    size_t rsOff = alloc(rsBytes);
    unsigned short* perBlockCnt = (unsigned short*)(ws + rsOff);
    int* rowStart   = (int*)(ws + rsOff);
    unsigned short* deg = (unsigned short*)(ws + alloc((size_t)N_PAD * 2));
    int* localE     = (int*)(ws + alloc((size_t)N_PAD * 4));
    int* blockSumsE = (int*)(ws + alloc((size_t)NSB * 4));
    int* blockBaseE = (int*)(ws + alloc((size_t)NSB * 4));
    unsigned* bucketData = (unsigned*)(ws + alloc((size_t)N_EDGES * 4));
    unsigned short* y = (unsigned short*)(ws + alloc((size_t)N_NODES * D_OUT * 2));
    float* yf       = (float*)(ws + alloc((size_t)N_NODES * D_OUT * 4));
    (void)ws_size; (void)in_sizes; (void)n_in; (void)out_size;

    const int T = 256;
    (void)hipMemsetAsync(nodeEntCnt, 0, (size_t)N_PAD * 4, stream);
    (void)hipMemsetAsync(refBits, 0, (size_t)(N_PAD / 8), stream);
    k_front<<<NBLK + CNT_BLKS + GEMM_BLKS, T, 0, stream>>>(dst4, perBlockCnt, x, nodeEntCnt,
                                                           refBits, feat, W, yf);
    k_scans<<<NSB + 64, 512, 0, stream>>>(nodeEntCnt, localE, blockSumsE, perBlockCnt, bucketTot);
    k_base2<<<2, 512, 0, stream>>>(bucketTot, bucketBase, blockSumsE, blockBaseE);
    k_scatters<<<NBLK + CNT_BLKS, T, 0, stream>>>(src4, dst4, bucketBase, perBlockCnt, bucketData,
                                                  x, localE, blockBaseE, entGrouped);
    k_bucket_csr<<<NBUCKET, T, 0, stream>>>(bucketData, bucketBase, refBits, rowStart, deg, yf, y);
    k_agg<<<((size_t)N_PAD * 64 + T - 1) / T, T, 0, stream>>>(
        entGrouped, localE, blockBaseE, rowStart, deg, bucketData, y, bsrc, out);
}